// Round 16
// baseline (97.625 us; speedup 1.0000x reference)
//
#include <hip/hip_runtime.h>
#include <cstdint>

#define SEQ    8192
#define DIN    1024
#define DOUT   128
#define KVTILE 32
#define QTILE  128
// Q is pre-scaled by 1/sqrt(128) * log2(e) at the QKV GEMM epilogue, so the
// attn kernel works entirely in log2-units (exp2, no LOG2E muls).
#define QK_SCALE 0.1275174246f

typedef unsigned short u16;
typedef __bf16 bf16x8 __attribute__((ext_vector_type(8)));
typedef float  f32x4  __attribute__((ext_vector_type(4)));
typedef float  f32x16 __attribute__((ext_vector_type(16)));
typedef unsigned short u16x8 __attribute__((ext_vector_type(8)));
typedef unsigned short u16x4 __attribute__((ext_vector_type(4)));
typedef unsigned int u32x2 __attribute__((ext_vector_type(2)));
typedef unsigned int u32x4 __attribute__((ext_vector_type(4)));

// f32 -> bf16 via native cast (compiler emits v_cvt_pk_bf16_f32, RNE)
__device__ __forceinline__ u16 bfc(float f) {
  return __builtin_bit_cast(u16, (__bf16)f);
}
__device__ __forceinline__ float bf2f(u16 u) {
  union { uint32_t u; float f; } c; c.u = ((uint32_t)u) << 16; return c.f;
}

__device__ __forceinline__ bf16x8 ldsu8(const u16* base, int byteoff) {
  return __builtin_bit_cast(bf16x8,
    *reinterpret_cast<const u16x8*>(reinterpret_cast<const char*>(base) + byteoff));
}
__device__ __forceinline__ bf16x8 glbu8(const u16* p) {
  return __builtin_bit_cast(bf16x8, *reinterpret_cast<const u16x8*>(p));
}

// async global->LDS DMA, 16B per lane; LDS dest = wave-uniform base + lane*16.
__device__ __forceinline__ void gload_lds16(const void* g, void* l) {
  __builtin_amdgcn_global_load_lds(
      (const __attribute__((address_space(1))) void*)g,
      (__attribute__((address_space(3))) void*)l, 16, 0, 0);
}

// ---------------------------------------------------------------- kernel 0
// W [1024][128] fp32  ->  Wt [3][128][1024] bf16 (transposed)
__global__ __launch_bounds__(256) void k_wtrans(const float* __restrict__ wq,
                                                const float* __restrict__ wk,
                                                const float* __restrict__ wv,
                                                u16* __restrict__ Wt) {
  const float* w = (blockIdx.y == 0) ? wq : (blockIdx.y == 1) ? wk : wv;
  int idx = blockIdx.x * 256 + threadIdx.x;      // over DIN*DOUT
  int k = idx >> 7, n = idx & 127;
  Wt[(size_t)blockIdx.y * (DOUT * DIN) + (size_t)n * DIN + k] = bfc(w[idx]);
}

// ---------------------------------------------------------------- kernel 0b
// X fp32 [8192][1024] -> Xb bf16 [8192][1024], coalesced. 8 elems/thread.
__global__ __launch_bounds__(256) void k_xcast(const float* __restrict__ x,
                                               u16* __restrict__ Xb) {
  size_t base = ((size_t)blockIdx.x * 256 + threadIdx.x) * 8;
  float4 lo = *reinterpret_cast<const float4*>(x + base);
  float4 hi = *reinterpret_cast<const float4*>(x + base + 4);
  u16x8 v = { bfc(lo.x), bfc(lo.y), bfc(lo.z), bfc(lo.w),
              bfc(hi.x), bfc(hi.y), bfc(hi.z), bfc(hi.w) };
  *reinterpret_cast<u16x8*>(Xb + base) = v;
}

// ---------------------------------------------------------------- kernel 1
// GEMM C[8192][384] = Xb[8192][1024] * Wt^T.  (byte-identical to round 7)
__global__ __launch_bounds__(256, 2) void k_gemm(const u16* __restrict__ Xb,
                                                 const u16* __restrict__ Wt,
                                                 u16* __restrict__ Q,
                                                 u16* __restrict__ K,
                                                 u16* __restrict__ Vt) {
  __shared__ __attribute__((aligned(16))) u16 As[2][64 * 128];   // 2x16 KB
  __shared__ __attribute__((aligned(16))) u16 Bs[2][96 * 128];   // 2x24 KB
  const int tid  = threadIdx.x;
  const int lane = tid & 63, wave = tid >> 6;
  const int lm   = lane & 15, g = lane >> 4;
  const int wm   = wave >> 1, wn = wave & 1;     // 2x2 wave grid
  const int m0   = blockIdx.x * 64;
  const int n0   = blockIdx.y * 96;
  const int swzr = (lm & 7) << 4;

  const int trow = tid >> 4;                     // 0..15
  const int tswz = ((tid & 15) << 4) ^ ((trow & 7) << 4);
  const char* baseA = (const char*)Xb + (size_t)(m0 + trow) * 2048 + tswz;
  const char* baseB = (const char*)Wt + (size_t)(n0 + trow) * 2048 + tswz;

  auto stage = [&](int buf, int kc) {
    const int kb = kc * 256;                     // 128 k * 2B
#pragma unroll
    for (int i = 0; i < 4; ++i)                  // A: 64 rows = 4 issues
      gload_lds16(baseA + kb + i * 32768, &As[buf][i * 2048 + wave * 512]);
#pragma unroll
    for (int j = 0; j < 6; ++j)                  // B: 96 rows = 6 issues
      gload_lds16(baseB + kb + j * 32768, &Bs[buf][j * 2048 + wave * 512]);
  };

  f32x4 acc[2][3];
#pragma unroll
  for (int s = 0; s < 2; ++s)
#pragma unroll
    for (int nb = 0; nb < 3; ++nb) acc[s][nb] = (f32x4){0.f, 0.f, 0.f, 0.f};

  auto compute = [&](int buf) {
    const u16* As_ = As[buf];
    const u16* Bs_ = Bs[buf];
    bf16x8 a[2][4], b[3][4];
#pragma unroll
    for (int s = 0; s < 2; ++s)
#pragma unroll
      for (int t = 0; t < 4; ++t)
        a[s][t] = ldsu8(As_, (wm * 32 + s * 16 + lm) * 256 +
                             ((t * 64 + 16 * g) ^ swzr));
#pragma unroll
    for (int nb = 0; nb < 3; ++nb)
#pragma unroll
      for (int t = 0; t < 4; ++t)
        b[nb][t] = ldsu8(Bs_, (wn * 48 + nb * 16 + lm) * 256 +
                              ((t * 64 + 16 * g) ^ swzr));
#pragma unroll
    for (int s = 0; s < 2; ++s)
#pragma unroll
      for (int nb = 0; nb < 3; ++nb)
#pragma unroll
        for (int t = 0; t < 4; ++t)
          acc[s][nb] = __builtin_amdgcn_mfma_f32_16x16x32_bf16(
              a[s][t], b[nb][t], acc[s][nb], 0, 0, 0);
  };

  stage(0, 0);
  asm volatile("s_waitcnt vmcnt(0)" ::: "memory");
  __syncthreads();

#pragma unroll
  for (int kc = 0; kc < 8; kc += 2) {
    if (kc + 1 < 8) stage(1, kc + 1);
    compute(0);
    asm volatile("s_waitcnt vmcnt(0)" ::: "memory");
    __syncthreads();
    if (kc + 2 < 8) stage(0, kc + 2);
    compute(1);
    asm volatile("s_waitcnt vmcnt(0)" ::: "memory");
    __syncthreads();
  }

  // epilogue: C/D layout col=lane&15, row=(lane>>4)*4+reg  [HW-verified]
#pragma unroll
  for (int s = 0; s < 2; ++s)
#pragma unroll
    for (int nb = 0; nb < 3; ++nb) {
      int n = n0 + wn * 48 + nb * 16 + lm;
      int which = n >> 7, col = n & 127;         // uniform per nb
#pragma unroll
      for (int r = 0; r < 4; ++r) {
        int m = m0 + wm * 32 + s * 16 + g * 4 + r;
        if (which == 0)       Q[(size_t)m * DOUT + col] = bfc(acc[s][nb][r] * QK_SCALE);
        else if (which == 1)  K[(size_t)m * DOUT + col] = bfc(acc[s][nb][r]);
        else                  Vt[(size_t)col * SEQ + m] = bfc(acc[s][nb][r]);
      }
    }
}

// ---------------------------------------------------------------- kernel 2
// Flash attention partials — r15 pipeline, 4-WAVE BLOCKS (occupancy fix).
// r15 post-mortem: no pipe saturated (MFMA 24%, VALU 39%, LDS <40%) and
// OccupancyPercent 17.5% = 3 blocks/CU x 2 waves = 6 waves/CU — latency-
// bound from wave starvation, not any structural convoy.  This round:
// QTILE=128 with 4 waves/block (256 thr) at the SAME 40KB LDS -> waves/CU
// = 4 x blocks/CU.  Split count is a RUNTIME arg (nsl2): nsplit=16 when
// the workspace fits the bigger partial buffer -> grid 1024 = 4 blocks/CU
// attempt (LDS caps 3) = 12 waves/CU; fallback nsplit=8 -> 8 waves/CU.
// Per-wave staging halves: 2 K-issues + 2 V-issues per tile -> counted
// wait becomes vmcnt(2) (own newest 2 = V(t+1); K(t+1),V(t) complete),
// wait-BEFORE-barrier exactly as r15's proof.
__global__ __launch_bounds__(256, 2) void k_attn(const u16* __restrict__ Q,
                                                 const u16* __restrict__ K,
                                                 const u16* __restrict__ Vt,
                                                 u16* __restrict__ Op,
                                                 float* __restrict__ Lb,
                                                 int nsl2) {
  __shared__ __attribute__((aligned(16))) u16 Ks[2][32 * 128];    // 2x8 KB
  __shared__ __attribute__((aligned(16))) u16 Vts[3][128 * 32];   // 3x8 KB
  const int tid  = threadIdx.x;
  const int lane = tid & 63, wave = tid >> 6;       // wave 0..3
  const int l31  = lane & 31, h = lane >> 5;
  const int bid  = blockIdx.x;
  const int nsplit = 1 << nsl2;
  const int split = bid & (nsplit - 1);             // XCD-friendly low bits
  const int m0   = (bid >> nsl2) * QTILE;
  const int kvbase = split * (SEQ >> nsl2);
  const int NIT = (SEQ >> nsl2) / KVTILE;           // 32 (ns=8) / 16 (ns=16)

  // K tile [32][128] (256B rows): wave w stages rows [w*8,+8), 2 issues.
  auto stageK = [&](int kb, int kv0) {
#pragma unroll
    for (int i = 0; i < 2; ++i) {
      int krow = wave * 8 + i * 4 + (lane >> 4);
      const char* gk = (const char*)K + ((size_t)(kv0 + krow) << 8) +
                       (((lane & 15) << 4) ^ ((krow & 7) << 4));
      gload_lds16(gk, &Ks[kb][wave * 1024 + i * 512]);
    }
  };
  // V tile [128][32] (64B rows): wave w stages rows [w*32,+32), 2 issues.
  auto stageV = [&](u16* vbuf, int kv0) {
#pragma unroll
    for (int i = 0; i < 2; ++i) {
      int vrow = wave * 32 + i * 16 + (lane >> 2);
      const char* gv = (const char*)Vt + (size_t)vrow * (SEQ * 2) +
                       (size_t)kv0 * 2 +
                       (((lane & 3) << 4) ^ (((vrow >> 1) & 3) << 4));
      gload_lds16(gv, vbuf + wave * 1024 + i * 512);
    }
  };

  // Q fragments: q-row = m0 + wave*32 + l31; k-elems t*16 + 8h + e
  bf16x8 qf[8];

  f32x16 o[4] = {};              // O[d=db*32+...][q=l31]
  float lr = 0.f;                // per-lane partial denominator (k-half)

  // ---- S^T = K Q^T for one 32-row K tile (8 K-steps, 2 indep chains)
  auto qk = [&](const u16* ks) -> f32x16 {
    f32x16 a0 = {}, a1 = {};
    const int rswz = (l31 & 7) << 4;
#pragma unroll
    for (int t = 0; t < 8; t += 2) {
      bf16x8 k0 = ldsu8(ks, l31 * 256 + ((t * 32 + 16 * h) ^ rswz));
      bf16x8 k1 = ldsu8(ks, l31 * 256 + (((t + 1) * 32 + 16 * h) ^ rswz));
      a0 = __builtin_amdgcn_mfma_f32_32x32x16_bf16(k0, qf[t], a0, 0, 0, 0);
      a1 = __builtin_amdgcn_mfma_f32_32x32x16_bf16(k1, qf[t + 1], a1, 0, 0, 0);
    }
    return a0 + a1;              // log2-units; lane: q=l31, 16 k-vals
  };

  // ---- no-max softmax + PV for one tile (s: 16 k-vals/lane; vs: V buf)
  auto smpv = [&](f32x16 s, const u16* vs) {
    float rsum = 0.f;
#pragma unroll
    for (int j = 0; j < 2; ++j) {         // kv = 16j + 8h + e
      const int base = j * 8;
      float e0 = exp2f(s[base + 0]);
      float e1 = exp2f(s[base + 1]);
      float e2 = exp2f(s[base + 2]);
      float e3 = exp2f(s[base + 3]);
      float e4 = exp2f(s[base + 4]);
      float e5 = exp2f(s[base + 5]);
      float e6 = exp2f(s[base + 6]);
      float e7 = exp2f(s[base + 7]);
      rsum += ((e0 + e1) + (e2 + e3)) + ((e4 + e5) + (e6 + e7));
      u16x4 wa = { bfc(e0), bfc(e1), bfc(e2), bfc(e3) };
      u16x4 wb = { bfc(e4), bfc(e5), bfc(e6), bfc(e7) };
      u32x2 A = __builtin_bit_cast(u32x2, wa);
      u32x2 B = __builtin_bit_cast(u32x2, wb);
      u32x2 r01 = __builtin_amdgcn_permlane32_swap(A.x, B.x, false, false);
      u32x2 r23 = __builtin_amdgcn_permlane32_swap(A.y, B.y, false, false);
      u32x4 fr = { r01.x, r23.x, r01.y, r23.y };
      bf16x8 pb = __builtin_bit_cast(bf16x8, fr);
#pragma unroll
      for (int db = 0; db < 4; ++db) {
        int vrow = db * 32 + l31;
        bf16x8 vb = ldsu8(vs, vrow * 64 +
                              ((32 * j + 16 * h) ^ (((vrow >> 1) & 3) << 4)));
        o[db] = __builtin_amdgcn_mfma_f32_32x32x16_bf16(vb, pb, o[db], 0, 0, 0);
      }
    }
    lr += rsum;
  };

  // ---- prologue: stage tiles 0,1; load Q; drain; QK(0)
  u16 *vA = Vts[0], *vB = Vts[1], *vC = Vts[2];
  stageK(0, kvbase);
  stageV(vA, kvbase);
  stageK(1, kvbase + KVTILE);
  stageV(vB, kvbase + KVTILE);
  {
    const u16* qp = Q + (size_t)(m0 + wave * 32 + l31) * DOUT + 8 * h;
#pragma unroll
    for (int t = 0; t < 8; ++t) qf[t] = glbu8(qp + t * 16);
  }
  asm volatile("s_waitcnt vmcnt(0)" ::: "memory");
  __syncthreads();
  f32x16 sA = qk(Ks[0]);
  f32x16 sB;

  for (int t = 0; t < NIT; t += 2) {
    const bool more = (t + 2 < NIT);
    // ---- sub-iter t (even): consume sA & V[vA]; produce sB = QK(t+1)
    if (more) asm volatile("s_waitcnt vmcnt(2) lgkmcnt(0)" ::: "memory");
    else      asm volatile("s_waitcnt vmcnt(0) lgkmcnt(0)" ::: "memory");
    __builtin_amdgcn_s_barrier();
    if (more) {
      stageK(0, kvbase + (t + 2) * KVTILE);      // Ks[(t+2)&1] = Ks[0]
      stageV(vC, kvbase + (t + 2) * KVTILE);
    }
    sB = qk(Ks[1]);                              // tile t+1 (t+1<NIT always)
    smpv(sA, vA);
    { u16* tp = vA; vA = vB; vB = vC; vC = tp; }

    // ---- sub-iter t+1 (odd): consume sB & V[vA]; produce sA = QK(t+2)
    if (more) asm volatile("s_waitcnt vmcnt(2) lgkmcnt(0)" ::: "memory");
    else      asm volatile("s_waitcnt vmcnt(0) lgkmcnt(0)" ::: "memory");
    __builtin_amdgcn_s_barrier();
    if (t + 3 < NIT) {
      stageK(1, kvbase + (t + 3) * KVTILE);      // Ks[(t+3)&1] = Ks[1]
      stageV(vC, kvbase + (t + 3) * KVTILE);
    }
    if (more) sA = qk(Ks[0]);                    // tile t+2
    smpv(sB, vA);
    { u16* tp = vA; vA = vB; vB = vC; vC = tp; }
  }

  // ---- epilogue: finish denominator (merge the two k-half lanes)
  lr += __shfl_xor(lr, 32);

  // store partials: lane holds O[d = db*32+8j+4h+c][q = m0+wave*32+l31]
  const size_t ob = (size_t)split * SEQ * DOUT;
  const int q = m0 + wave * 32 + l31;
#pragma unroll
  for (int db = 0; db < 4; ++db)
#pragma unroll
    for (int j = 0; j < 4; ++j) {
      u16x4 w = { bfc(o[db][4 * j + 0]), bfc(o[db][4 * j + 1]),
                  bfc(o[db][4 * j + 2]), bfc(o[db][4 * j + 3]) };
      *reinterpret_cast<u16x4*>(Op + ob + (size_t)q * DOUT +
                                db * 32 + 8 * j + 4 * h) = w;
    }
  if (h == 0) Lb[split * SEQ + q] = lr;
}

// ---------------------------------------------------------------- kernel 3
// combine: plain sums (no-max softmax -> all splits share scale 2^0)
__global__ __launch_bounds__(256) void k_combine(const u16* __restrict__ Op,
                                                 const float* __restrict__ Lb,
                                                 float* __restrict__ out,
                                                 int nsplit) {
  int idx = blockIdx.x * 256 + threadIdx.x;   // over SEQ*DOUT
  int srow = idx >> 7;
  float num = 0.f, den = 0.f;
  const size_t st = (size_t)SEQ * DOUT;
  for (int s = 0; s < nsplit; ++s) {
    den += Lb[s * SEQ + srow];
    num += bf2f(Op[s * st + idx]);
  }
  out[idx] = num / den;
}

// ---------------------------------------------------------------- launch
extern "C" void kernel_launch(void* const* d_in, const int* in_sizes, int n_in,
                              void* d_out, int out_size, void* d_ws, size_t ws_size,
                              hipStream_t stream) {
  const float* x  = (const float*)d_in[0];
  const float* wq = (const float*)d_in[1];
  const float* wk = (const float*)d_in[2];
  const float* wv = (const float*)d_in[3];
  char* ws = (char*)d_ws;

  // workspace layout (bytes):
  //  [0,      768K)        Wt bf16 [3][128][1024]
  //  [768K,   +2M)         Q  bf16 [8192][128]   (pre-scaled by QK_SCALE)
  //  [768K+2M,+2M)         K  bf16 [8192][128]
  //  [768K+4M,+2M)         Vt bf16 [128][8192]       (ends 6.75M)
  //  [6.75M,  +512K)       Lb f32 [<=16][8192]       (ends 7.25M)
  //  [7.25M,  +nsplit*2M)  Op bf16 [nsplit][8192][128]  ALIASED with
  //                        Xb bf16 [8192][1024] (16M; Xb dead before k_attn)
  // nsplit = 16 if ws_size fits 7.25M + 32M (~41.2MB), else 8 (23.25MB,
  // the footprint proven in all passing rounds).
  const size_t MB = (size_t)1 << 20;
  u16*   Wt = (u16*)(ws);
  u16*   Q  = (u16*)(ws + 768 * 1024);
  u16*   K  = (u16*)(ws + 768 * 1024 + 2 * MB);
  u16*   Vt = (u16*)(ws + 768 * 1024 + 4 * MB);
  float* Lb = (float*)(ws + 768 * 1024 + 6 * MB);
  u16*   Xb = (u16*)(ws + 7 * MB + 256 * 1024);
  u16*   Op = (u16*)(ws + 7 * MB + 256 * 1024);
  float* out = (float*)d_out;

  const size_t need16 = 7 * MB + 256 * 1024 + 32 * MB;   // 41.2 MB
  const int nsl2 = (ws_size >= need16) ? 4 : 3;
  const int nsplit = 1 << nsl2;

  k_wtrans<<<dim3((DIN * DOUT) / 256, 3), 256, 0, stream>>>(wq, wk, wv, Wt);
  k_xcast<<<dim3((SEQ * DIN) / (256 * 8)), 256, 0, stream>>>(x, Xb);
  k_gemm<<<dim3(SEQ / 64, 4), 256, 0, stream>>>(Xb, Wt, Q, K, Vt);
  k_attn<<<dim3((SEQ / QTILE) * nsplit), 256, 0, stream>>>(Q, K, Vt, Op, Lb, nsl2);
  k_combine<<<dim3((SEQ * DOUT) / 256), 256, 0, stream>>>(Op, Lb, out, nsplit);
}

// Round 17
// 86.536 us; speedup vs baseline: 1.1281x; 1.1281x over previous
//
#include <hip/hip_runtime.h>
#include <cstdint>

#define SEQ    8192
#define DIN    1024
#define DOUT   128
#define NSPLIT 8
#define KVTILE 32
#define QTILE  64
// Q is pre-scaled by 1/sqrt(128) * log2(e) at the QKV GEMM epilogue, so the
// attn kernel works entirely in log2-units (exp2, no LOG2E muls).
#define QK_SCALE 0.1275174246f

typedef unsigned short u16;
typedef __bf16 bf16x8 __attribute__((ext_vector_type(8)));
typedef float  f32x4  __attribute__((ext_vector_type(4)));
typedef float  f32x16 __attribute__((ext_vector_type(16)));
typedef unsigned short u16x8 __attribute__((ext_vector_type(8)));
typedef unsigned short u16x4 __attribute__((ext_vector_type(4)));
typedef unsigned int u32x2 __attribute__((ext_vector_type(2)));
typedef unsigned int u32x4 __attribute__((ext_vector_type(4)));

// f32 -> bf16 via native cast (compiler emits v_cvt_pk_bf16_f32, RNE)
__device__ __forceinline__ u16 bfc(float f) {
  return __builtin_bit_cast(u16, (__bf16)f);
}
__device__ __forceinline__ float bf2f(u16 u) {
  union { uint32_t u; float f; } c; c.u = ((uint32_t)u) << 16; return c.f;
}

__device__ __forceinline__ bf16x8 ldsu8(const u16* base, int byteoff) {
  return __builtin_bit_cast(bf16x8,
    *reinterpret_cast<const u16x8*>(reinterpret_cast<const char*>(base) + byteoff));
}
__device__ __forceinline__ bf16x8 glbu8(const u16* p) {
  return __builtin_bit_cast(bf16x8, *reinterpret_cast<const u16x8*>(p));
}

// async global->LDS DMA, 16B per lane; LDS dest = wave-uniform base + lane*16.
__device__ __forceinline__ void gload_lds16(const void* g, void* l) {
  __builtin_amdgcn_global_load_lds(
      (const __attribute__((address_space(1))) void*)g,
      (__attribute__((address_space(3))) void*)l, 16, 0, 0);
}

// ---------------------------------------------------------------- kernel 0
// W [1024][128] fp32  ->  Wt [3][128][1024] bf16 (transposed)
__global__ __launch_bounds__(256) void k_wtrans(const float* __restrict__ wq,
                                                const float* __restrict__ wk,
                                                const float* __restrict__ wv,
                                                u16* __restrict__ Wt) {
  const float* w = (blockIdx.y == 0) ? wq : (blockIdx.y == 1) ? wk : wv;
  int idx = blockIdx.x * 256 + threadIdx.x;      // over DIN*DOUT
  int k = idx >> 7, n = idx & 127;
  Wt[(size_t)blockIdx.y * (DOUT * DIN) + (size_t)n * DIN + k] = bfc(w[idx]);
}

// ---------------------------------------------------------------- kernel 1
// GEMM C[8192][384] = X[8192][1024](f32) * Wt^T — xcast FUSED (r17).
// A path: reg-staged (T14 split): 8x float4 loads issued BEFORE compute,
// cvt+8x ds_write_b64 AFTER, into the SAME swizzled layout the read path
// expects: LDS byte(row,c) holds global byte col (c ^ ((row&7)<<4));
// 8B chunks preserve within-granule offset (XOR touches bits 4-6 only).
// B path: gload_lds, unchanged.  Saves k_xcast's 48MB round-trip.
__global__ __launch_bounds__(256, 2) void k_gemm(const float* __restrict__ x,
                                                 const u16* __restrict__ Wt,
                                                 u16* __restrict__ Q,
                                                 u16* __restrict__ K,
                                                 u16* __restrict__ Vt) {
  __shared__ __attribute__((aligned(16))) u16 As[2][64 * 128];   // 2x16 KB
  __shared__ __attribute__((aligned(16))) u16 Bs[2][96 * 128];   // 2x24 KB
  const int tid  = threadIdx.x;
  const int lane = tid & 63, wave = tid >> 6;
  const int lm   = lane & 15, g = lane >> 4;
  const int wm   = wave >> 1, wn = wave & 1;     // 2x2 wave grid
  const int m0   = blockIdx.x * 64;
  const int n0   = blockIdx.y * 96;
  const int swzr = (lm & 7) << 4;

  // A staging geometry: thread covers row = tid>>2 (0..63), f32 bytes
  // (tid&3)*16 + i*64 within the row (i=0..7) -> bf16 col (tid&3)*8 + i*32.
  const int arow = tid >> 2, acol = tid & 3;
  const float* xbase = x + (size_t)(m0 + arow) * DIN + acol * 4;
  // B staging geometry (unchanged from r7)
  const int trow = tid >> 4;                     // 0..15
  const int tswz = ((tid & 15) << 4) ^ ((trow & 7) << 4);
  const char* baseB = (const char*)Wt + (size_t)(n0 + trow) * 2048 + tswz;

  float4 fa[8];
  auto stage_load = [&](int bbuf, int kc) {      // issue A f32 + B gloads
    const float* xp = xbase + kc * 128;
#pragma unroll
    for (int i = 0; i < 8; ++i)
      fa[i] = *reinterpret_cast<const float4*>(xp + i * 16);
    const int kb = kc * 256;                     // 128 k * 2B
#pragma unroll
    for (int j = 0; j < 6; ++j)                  // B: 96 rows = 6 issues
      gload_lds16(baseB + kb + j * 32768, &Bs[bbuf][j * 2048 + wave * 512]);
  };
  auto stage_write = [&](int abuf) {             // cvt + swizzled ds_write
    char* dst = reinterpret_cast<char*>(As[abuf]) + arow * 256;
    const int sw = (arow & 7) << 4;
#pragma unroll
    for (int i = 0; i < 8; ++i) {
      u16x4 w = { bfc(fa[i].x), bfc(fa[i].y), bfc(fa[i].z), bfc(fa[i].w) };
      *reinterpret_cast<u16x4*>(dst + ((acol * 8 + i * 32) ^ sw)) = w;
    }
  };

  f32x4 acc[2][3];
#pragma unroll
  for (int s = 0; s < 2; ++s)
#pragma unroll
    for (int nb = 0; nb < 3; ++nb) acc[s][nb] = (f32x4){0.f, 0.f, 0.f, 0.f};

  auto compute = [&](int buf) {
    const u16* As_ = As[buf];
    const u16* Bs_ = Bs[buf];
    bf16x8 a[2][4], b[3][4];
#pragma unroll
    for (int s = 0; s < 2; ++s)
#pragma unroll
      for (int t = 0; t < 4; ++t)
        a[s][t] = ldsu8(As_, (wm * 32 + s * 16 + lm) * 256 +
                             ((t * 64 + 16 * g) ^ swzr));
#pragma unroll
    for (int nb = 0; nb < 3; ++nb)
#pragma unroll
      for (int t = 0; t < 4; ++t)
        b[nb][t] = ldsu8(Bs_, (wn * 48 + nb * 16 + lm) * 256 +
                              ((t * 64 + 16 * g) ^ swzr));
#pragma unroll
    for (int s = 0; s < 2; ++s)
#pragma unroll
      for (int nb = 0; nb < 3; ++nb)
#pragma unroll
        for (int t = 0; t < 4; ++t)
          acc[s][nb] = __builtin_amdgcn_mfma_f32_16x16x32_bf16(
              a[s][t], b[nb][t], acc[s][nb], 0, 0, 0);
  };

  stage_load(0, 0);
  stage_write(0);
  asm volatile("s_waitcnt vmcnt(0)" ::: "memory");
  __syncthreads();

#pragma unroll
  for (int kc = 0; kc < 8; kc += 2) {
    if (kc + 1 < 8) stage_load(1, kc + 1);       // loads fly under compute
    compute(0);
    if (kc + 1 < 8) stage_write(1);
    asm volatile("s_waitcnt vmcnt(0)" ::: "memory");
    __syncthreads();
    if (kc + 2 < 8) stage_load(0, kc + 2);
    compute(1);
    if (kc + 2 < 8) stage_write(0);
    asm volatile("s_waitcnt vmcnt(0)" ::: "memory");
    __syncthreads();
  }

  // epilogue: C/D layout col=lane&15, row=(lane>>4)*4+reg  [HW-verified]
#pragma unroll
  for (int s = 0; s < 2; ++s)
#pragma unroll
    for (int nb = 0; nb < 3; ++nb) {
      int n = n0 + wn * 48 + nb * 16 + lm;
      int which = n >> 7, col = n & 127;         // uniform per nb
#pragma unroll
      for (int r = 0; r < 4; ++r) {
        int m = m0 + wm * 32 + s * 16 + g * 4 + r;
        if (which == 0)       Q[(size_t)m * DOUT + col] = bfc(acc[s][nb][r] * QK_SCALE);
        else if (which == 1)  K[(size_t)m * DOUT + col] = bfc(acc[s][nb][r]);
        else                  Vt[(size_t)col * SEQ + m] = bfc(acc[s][nb][r]);
      }
    }
}

// ---------------------------------------------------------------- kernel 2
// Flash attention partials — byte-identical to round 15 (measured 57.0us,
// the best of 9 structural variants r8-r16).  2-wave blocks, QTILE=64,
// KVTILE=32, K dbuf + V tribuf (40KB), QK(t+1) before SM(t)/PV(t),
// counted vmcnt(4) (never 0 in main loop), no-max softmax (exact after
// final division), permlane P-packing, XCD-local split.
__global__ __launch_bounds__(128, 2) void k_attn(const u16* __restrict__ Q,
                                                 const u16* __restrict__ K,
                                                 const u16* __restrict__ Vt,
                                                 u16* __restrict__ Op,
                                                 float* __restrict__ Lb) {
  __shared__ __attribute__((aligned(16))) u16 Ks[2][32 * 128];    // 2x8 KB
  __shared__ __attribute__((aligned(16))) u16 Vts[3][128 * 32];   // 3x8 KB
  const int tid  = threadIdx.x;
  const int lane = tid & 63, wave = tid >> 6;       // wave 0..1
  const int l31  = lane & 31, h = lane >> 5;
  const int bid  = blockIdx.x;
  const int split = bid & 7;                        // XCD-local split
  const int m0   = (bid >> 3) * QTILE;
  const int kvbase = split * (SEQ / NSPLIT);
  const int NIT = (SEQ / NSPLIT) / KVTILE;          // 32

  auto stageK = [&](int kb, int kv0) {
#pragma unroll
    for (int i = 0; i < 4; ++i) {
      int krow = wave * 16 + i * 4 + (lane >> 4);
      const char* gk = (const char*)K + ((size_t)(kv0 + krow) << 8) +
                       (((lane & 15) << 4) ^ ((krow & 7) << 4));
      gload_lds16(gk, &Ks[kb][wave * 2048 + i * 512]);
    }
  };
  auto stageV = [&](u16* vbuf, int kv0) {
#pragma unroll
    for (int i = 0; i < 4; ++i) {
      int vrow = wave * 64 + i * 16 + (lane >> 2);
      const char* gv = (const char*)Vt + (size_t)vrow * (SEQ * 2) +
                       (size_t)kv0 * 2 +
                       (((lane & 3) << 4) ^ (((vrow >> 1) & 3) << 4));
      gload_lds16(gv, vbuf + wave * 2048 + i * 512);
    }
  };

  // Q fragments: q-row = m0 + wave*32 + l31; k-elems t*16 + 8h + e
  bf16x8 qf[8];

  f32x16 o[4] = {};              // O[d=db*32+...][q=l31]
  float lr = 0.f;                // per-lane partial denominator (k-half)

  auto qk = [&](const u16* ks) -> f32x16 {
    f32x16 a0 = {}, a1 = {};
    const int rswz = (l31 & 7) << 4;
#pragma unroll
    for (int t = 0; t < 8; t += 2) {
      bf16x8 k0 = ldsu8(ks, l31 * 256 + ((t * 32 + 16 * h) ^ rswz));
      bf16x8 k1 = ldsu8(ks, l31 * 256 + (((t + 1) * 32 + 16 * h) ^ rswz));
      a0 = __builtin_amdgcn_mfma_f32_32x32x16_bf16(k0, qf[t], a0, 0, 0, 0);
      a1 = __builtin_amdgcn_mfma_f32_32x32x16_bf16(k1, qf[t + 1], a1, 0, 0, 0);
    }
    return a0 + a1;              // log2-units; lane: q=l31, 16 k-vals
  };

  auto smpv = [&](f32x16 s, const u16* vs) {
    float rsum = 0.f;
#pragma unroll
    for (int j = 0; j < 2; ++j) {         // kv = 16j + 8h + e
      const int base = j * 8;
      float e0 = exp2f(s[base + 0]);
      float e1 = exp2f(s[base + 1]);
      float e2 = exp2f(s[base + 2]);
      float e3 = exp2f(s[base + 3]);
      float e4 = exp2f(s[base + 4]);
      float e5 = exp2f(s[base + 5]);
      float e6 = exp2f(s[base + 6]);
      float e7 = exp2f(s[base + 7]);
      rsum += ((e0 + e1) + (e2 + e3)) + ((e4 + e5) + (e6 + e7));
      u16x4 wa = { bfc(e0), bfc(e1), bfc(e2), bfc(e3) };
      u16x4 wb = { bfc(e4), bfc(e5), bfc(e6), bfc(e7) };
      u32x2 A = __builtin_bit_cast(u32x2, wa);
      u32x2 B = __builtin_bit_cast(u32x2, wb);
      u32x2 r01 = __builtin_amdgcn_permlane32_swap(A.x, B.x, false, false);
      u32x2 r23 = __builtin_amdgcn_permlane32_swap(A.y, B.y, false, false);
      u32x4 fr = { r01.x, r23.x, r01.y, r23.y };
      bf16x8 pb = __builtin_bit_cast(bf16x8, fr);
#pragma unroll
      for (int db = 0; db < 4; ++db) {
        int vrow = db * 32 + l31;
        bf16x8 vb = ldsu8(vs, vrow * 64 +
                              ((32 * j + 16 * h) ^ (((vrow >> 1) & 3) << 4)));
        o[db] = __builtin_amdgcn_mfma_f32_32x32x16_bf16(vb, pb, o[db], 0, 0, 0);
      }
    }
    lr += rsum;
  };

  // ---- prologue: stage tiles 0,1; load Q; drain; QK(0)
  u16 *vA = Vts[0], *vB = Vts[1], *vC = Vts[2];
  stageK(0, kvbase);
  stageV(vA, kvbase);
  stageK(1, kvbase + KVTILE);
  stageV(vB, kvbase + KVTILE);
  {
    const u16* qp = Q + (size_t)(m0 + wave * 32 + l31) * DOUT + 8 * h;
#pragma unroll
    for (int t = 0; t < 8; ++t) qf[t] = glbu8(qp + t * 16);
  }
  asm volatile("s_waitcnt vmcnt(0)" ::: "memory");
  __syncthreads();
  f32x16 sA = qk(Ks[0]);
  f32x16 sB;

  for (int t = 0; t < NIT; t += 2) {
    const bool more = (t + 2 < NIT);
    // ---- sub-iter t (even): consume sA & V[vA]; produce sB = QK(t+1)
    if (more) asm volatile("s_waitcnt vmcnt(4) lgkmcnt(0)" ::: "memory");
    else      asm volatile("s_waitcnt vmcnt(0) lgkmcnt(0)" ::: "memory");
    __builtin_amdgcn_s_barrier();
    if (more) {
      stageK(0, kvbase + (t + 2) * KVTILE);      // Ks[(t+2)&1] = Ks[0]
      stageV(vC, kvbase + (t + 2) * KVTILE);
    }
    sB = qk(Ks[1]);                              // tile t+1 (t+1<NIT always)
    smpv(sA, vA);
    { u16* tp = vA; vA = vB; vB = vC; vC = tp; }

    // ---- sub-iter t+1 (odd): consume sB & V[vA]; produce sA = QK(t+2)
    if (more) asm volatile("s_waitcnt vmcnt(4) lgkmcnt(0)" ::: "memory");
    else      asm volatile("s_waitcnt vmcnt(0) lgkmcnt(0)" ::: "memory");
    __builtin_amdgcn_s_barrier();
    if (t + 3 < NIT) {
      stageK(1, kvbase + (t + 3) * KVTILE);      // Ks[(t+3)&1] = Ks[1]
      stageV(vC, kvbase + (t + 3) * KVTILE);
    }
    if (more) sA = qk(Ks[0]);                    // tile t+2
    smpv(sB, vA);
    { u16* tp = vA; vA = vB; vB = vC; vC = tp; }
  }

  // ---- epilogue: finish denominator (merge the two k-half lanes)
  lr += __shfl_xor(lr, 32);

  // store partials: lane holds O[d = db*32+8j+4h+c][q = m0+wave*32+l31]
  const size_t ob = (size_t)split * SEQ * DOUT;
  const int q = m0 + wave * 32 + l31;
#pragma unroll
  for (int db = 0; db < 4; ++db)
#pragma unroll
    for (int j = 0; j < 4; ++j) {
      u16x4 w = { bfc(o[db][4 * j + 0]), bfc(o[db][4 * j + 1]),
                  bfc(o[db][4 * j + 2]), bfc(o[db][4 * j + 3]) };
      *reinterpret_cast<u16x4*>(Op + ob + (size_t)q * DOUT +
                                db * 32 + 8 * j + 4 * h) = w;
    }
  if (h == 0) Lb[split * SEQ + q] = lr;
}

// ---------------------------------------------------------------- kernel 3
// combine, vectorized (r17): thread owns 8 consecutive outputs; 8x u16x8
// split loads + 2x float4 stores (was 8 scalar u16 loads + 1 scalar store).
__global__ __launch_bounds__(256) void k_combine(const u16* __restrict__ Op,
                                                 const float* __restrict__ Lb,
                                                 float* __restrict__ out) {
  int e0 = (blockIdx.x * 256 + threadIdx.x) * 8;   // over SEQ*DOUT
  int srow = e0 >> 7;                              // 8 elems share a row
  float den = 0.f;
  float acc[8] = {};
  const size_t st = (size_t)SEQ * DOUT;
#pragma unroll
  for (int s = 0; s < NSPLIT; ++s) {
    den += Lb[s * SEQ + srow];
    u16x8 v = *reinterpret_cast<const u16x8*>(Op + s * st + e0);
#pragma unroll
    for (int i = 0; i < 8; ++i) acc[i] += bf2f(v[i]);
  }
  float r = 1.f / den;
  float4 o0 = { acc[0] * r, acc[1] * r, acc[2] * r, acc[3] * r };
  float4 o1 = { acc[4] * r, acc[5] * r, acc[6] * r, acc[7] * r };
  *reinterpret_cast<float4*>(out + e0) = o0;
  *reinterpret_cast<float4*>(out + e0 + 4) = o1;
}

// ---------------------------------------------------------------- launch
extern "C" void kernel_launch(void* const* d_in, const int* in_sizes, int n_in,
                              void* d_out, int out_size, void* d_ws, size_t ws_size,
                              hipStream_t stream) {
  const float* x  = (const float*)d_in[0];
  const float* wq = (const float*)d_in[1];
  const float* wk = (const float*)d_in[2];
  const float* wv = (const float*)d_in[3];
  char* ws = (char*)d_ws;

  // workspace layout (bytes), total exactly 23.25 MiB (proven footprint):
  //  [0,      768K)        Wt bf16 [3][128][1024]
  //  [768K,   +2M)         Q  bf16 [8192][128]   (pre-scaled by QK_SCALE)
  //  [768K+2M,+2M)         K  bf16 [8192][128]
  //  [768K+4M,+2M)         Vt bf16 [128][8192]       (ends 6.75M)
  //  [6.75M,  +256K)       (spare)
  //  [6.75M+256K, +256K)   Lb f32 [8][8192]          (ends 7.25M)
  //  [7.25M,  +16M)        Op bf16 [8][8192][128]
  const size_t MB = (size_t)1 << 20;
  u16*   Wt = (u16*)(ws);
  u16*   Q  = (u16*)(ws + 768 * 1024);
  u16*   K  = (u16*)(ws + 768 * 1024 + 2 * MB);
  u16*   Vt = (u16*)(ws + 768 * 1024 + 4 * MB);
  float* Lb = (float*)(ws + 768 * 1024 + 6 * MB + 256 * 1024);
  u16*   Op = (u16*)(ws + 7 * MB + 256 * 1024);
  float* out = (float*)d_out;

  k_wtrans<<<dim3((DIN * DOUT) / 256, 3), 256, 0, stream>>>(wq, wk, wv, Wt);
  k_gemm<<<dim3(SEQ / 64, 4), 256, 0, stream>>>(x, Wt, Q, K, Vt);
  k_attn<<<dim3((SEQ / QTILE) * NSPLIT), 128, 0, stream>>>(Q, K, Vt, Op, Lb);
  k_combine<<<dim3((SEQ * DOUT) / (256 * 8)), 256, 0, stream>>>(Op, Lb, out);
}